// Round 10
// baseline (130.085 us; speedup 1.0000x reference)
//
#include <hip/hip_runtime.h>

#define BATCH   32
#define DIM     128
#define NBASES  8
#define SSTEPS  128
#define LDA     136   // padded row (shorts): 272 B stride -> 4-bank shift/row

typedef __attribute__((ext_vector_type(8))) short s8v;   // 8 bf16 (4 VGPR)
typedef __attribute__((ext_vector_type(4))) float f4v;   // MFMA acc

__device__ __forceinline__ f4v mf(s8v a, s8v b, f4v c) {
    return __builtin_amdgcn_mfma_f32_16x16x32_bf16(a, b, c, 0, 0, 0);
}
__device__ __forceinline__ s8v ld8(const short* p) {
    return *reinterpret_cast<const s8v*>(p);
}
__device__ __forceinline__ float upbf(short h) {
    return __uint_as_float(((unsigned)(unsigned short)h) << 16);
}
// split fp32 -> bf16 hi + bf16 lo (truncation; dropped residual ~2^-16 rel)
__device__ __forceinline__ void splitbf(float v, short& hi, short& lo) {
    const unsigned u = __float_as_uint(v);
    hi = (short)(u >> 16);
    const float fh = __uint_as_float(u & 0xffff0000u);
    lo = (short)(__float_as_uint(v - fh) >> 16);
}
__device__ __forceinline__ void put2(short* __restrict__ hi, short* __restrict__ lo,
                                     int idx, float v) {
    short h, l; splitbf(v, h, l); hi[idx] = h; lo[idx] = l;
}

__device__ __forceinline__ void write_out(float* __restrict__ outF, int b, int sidx,
                                          int o, int c, float val,
                                          int interleaved, int out_size)
{
    if (interleaved) {
        const int oi = ((b * SSTEPS + sidx) * DIM + o) * 2 + c;
        if (oi < out_size) outF[oi] = val;
    } else if (c == 0) {
        const int oi = (b * SSTEPS + sidx) * DIM + o;
        if (oi < out_size) outF[oi] = val;
    }
}

// ---- full 128x128x128 split-bf16 MFMA matmul: 16 waves, wave = 32x32 tile ----
// A from "norm" planes (A[m][k] at m*LDA+k), B from "trans" planes (B^T row-major).
__device__ __forceinline__ void mm_full(const short* __restrict__ Ah,
                                        const short* __restrict__ Al,
                                        const short* __restrict__ Bh,
                                        const short* __restrict__ Bl,
                                        f4v acc[2][2], int rb, int cb, int lane)
{
    const int l15 = lane & 15, quad = lane >> 4;
    #pragma unroll
    for (int kk = 0; kk < DIM; kk += 32) {
        const int ko = kk + quad * 8;
        s8v ah[2], al[2], bh[2], bl[2];
        #pragma unroll
        for (int mi = 0; mi < 2; ++mi) {
            ah[mi] = ld8(Ah + (rb + mi * 16 + l15) * LDA + ko);
            al[mi] = ld8(Al + (rb + mi * 16 + l15) * LDA + ko);
        }
        #pragma unroll
        for (int ni = 0; ni < 2; ++ni) {
            bh[ni] = ld8(Bh + (cb + ni * 16 + l15) * LDA + ko);
            bl[ni] = ld8(Bl + (cb + ni * 16 + l15) * LDA + ko);
        }
        #pragma unroll
        for (int mi = 0; mi < 2; ++mi)
            #pragma unroll
            for (int ni = 0; ni < 2; ++ni) {
                acc[mi][ni] = mf(ah[mi], bh[ni], acc[mi][ni]);
                acc[mi][ni] = mf(ah[mi], bl[ni], acc[mi][ni]);
                acc[mi][ni] = mf(al[mi], bh[ni], acc[mi][ni]);
            }
    }
}

// ---- 128x16 strip x 128 MFMA (seeds/windows): wave = strip s, comp ci ----
__device__ __forceinline__ f4v mm_rw(const short* __restrict__ Ah,
                                     const short* __restrict__ Al,
                                     const short* __restrict__ Hh,
                                     const short* __restrict__ Hl,
                                     int s, int ci, int lane)
{
    const int l15 = lane & 15, quad = lane >> 4;
    f4v acc = {0.f, 0.f, 0.f, 0.f};
    #pragma unroll
    for (int kk = 0; kk < DIM; kk += 32) {
        const int ko = kk + quad * 8;
        const s8v ah = ld8(Ah + (s * 16 + l15) * LDA + ko);
        const s8v al = ld8(Al + (s * 16 + l15) * LDA + ko);
        const s8v bh = ld8(Hh + (ci * 16 + l15) * LDA + ko);
        const s8v bl = ld8(Hl + (ci * 16 + l15) * LDA + ko);
        acc = mf(ah, bh, acc);
        acc = mf(ah, bl, acc);
        acc = mf(al, bh, acc);
    }
    return acc;
}

// ============ whole problem: 1 block = 1 batch, MFMA chain in LDS ============
__global__ __launch_bounds__(1024)
void htg_mfma(const float* __restrict__ z0r, const float* __restrict__ z0i,
              const float* __restrict__ ts,  const float* __restrict__ kco,
              const float* __restrict__ rco, const float* __restrict__ alp,
              const float* __restrict__ bet, const float* __restrict__ KB,
              const float* __restrict__ RB,  float* __restrict__ outF,
              int interleaved, int out_size)
{
    __shared__ short nm_hi[DIM * LDA], nm_lo[DIM * LDA];   // row-major planes
    __shared__ short tr_hi[DIM * LDA], tr_lo[DIM * LDA];   // transposed planes
    __shared__ short ht_hi[32 * LDA],  ht_lo[32 * LDA];    // u-table (slot rows)
    __shared__ float s_z[2 * DIM];

    const int b = blockIdx.x, t = threadIdx.x;
    const int w = t >> 6, lane = t & 63;
    const int l15 = lane & 15, quad = lane >> 4;
    const int rb = (w & 3) * 32, cb = (w >> 2) * 32;   // mm_full tile
    const int sst = w >> 1, ci = w & 1;                // mm_rw strip/comp
    const f4v z4 = {0.f, 0.f, 0.f, 0.f};

    // ---- S1: Rsum -> trans planes; Ksum -> norm planes; z -> s_z ----
    {
        float rc[NBASES], kc[NBASES];
        #pragma unroll
        for (int n = 0; n < NBASES; ++n) {
            rc[n] = rco[b * NBASES + n];
            kc[n] = kco[b * NBASES + n];
        }
        #pragma unroll
        for (int q = 0; q < 4; ++q) {
            const int e = q * 4096 + t * 4;
            float4 r4 = {0.f, 0.f, 0.f, 0.f}, k4 = {0.f, 0.f, 0.f, 0.f};
            #pragma unroll
            for (int n = 0; n < NBASES; ++n) {
                const float4 rv = *reinterpret_cast<const float4*>(RB + n * DIM * DIM + e);
                const float4 kv = *reinterpret_cast<const float4*>(KB + n * DIM * DIM + e);
                r4.x += rc[n] * rv.x; r4.y += rc[n] * rv.y;
                r4.z += rc[n] * rv.z; r4.w += rc[n] * rv.w;
                k4.x += kc[n] * kv.x; k4.y += kc[n] * kv.y;
                k4.z += kc[n] * kv.z; k4.w += kc[n] * kv.w;
            }
            const int r = e >> 7, c = e & 127;
            const float rr[4] = {r4.x, r4.y, r4.z, r4.w};
            const float kk[4] = {k4.x, k4.y, k4.z, k4.w};
            #pragma unroll
            for (int j = 0; j < 4; ++j) {
                put2(tr_hi, tr_lo, (c + j) * LDA + r, rr[j]);
                put2(nm_hi, nm_lo, r * LDA + c + j, kk[j]);
            }
        }
        if (t < 2 * DIM)
            s_z[t] = (t < DIM) ? z0r[b * DIM + t] : z0i[b * DIM + (t - DIM)];
    }
    __syncthreads();

    f4v acc[2][2];

    // ---- Op1: gram = R^T@R (both frags from trans(R));
    //      X = (alpha*(K - K^T) - beta*gram)*dt + 1e-6*I ----
    #pragma unroll
    for (int i = 0; i < 2; ++i)
        #pragma unroll
        for (int j = 0; j < 2; ++j) acc[i][j] = z4;
    mm_full(tr_hi, tr_lo, tr_hi, tr_lo, acc, rb, cb, lane);
    __syncthreads();
    {
        const float alpha = alp[b], beta = bet[b], dtf = ts[0];
        #pragma unroll
        for (int mi = 0; mi < 2; ++mi)
            #pragma unroll
            for (int ni = 0; ni < 2; ++ni)
                #pragma unroll
                for (int r = 0; r < 4; ++r) {
                    const int row = rb + mi * 16 + quad * 4 + r;
                    const int col = cb + ni * 16 + l15;
                    const float k1 = upbf(nm_hi[row * LDA + col]) + upbf(nm_lo[row * LDA + col]);
                    const float k2 = upbf(nm_hi[col * LDA + row]) + upbf(nm_lo[col * LDA + row]);
                    float x = (alpha * (k1 - k2) - beta * acc[mi][ni][r]) * dtf;
                    if (row == col) x += 1e-6f;
                    acc[mi][ni][r] = x;
                }
    }
    __syncthreads();
    #pragma unroll
    for (int mi = 0; mi < 2; ++mi)
        #pragma unroll
        for (int ni = 0; ni < 2; ++ni)
            #pragma unroll
            for (int r = 0; r < 4; ++r) {
                const int row = rb + mi * 16 + quad * 4 + r;
                const int col = cb + ni * 16 + l15;
                put2(nm_hi, nm_lo, row * LDA + col, acc[mi][ni][r]);   // X
                put2(tr_hi, tr_lo, col * LDA + row, acc[mi][ni][r]);   // X^T
            }
    __syncthreads();

    // ---- Op2: C = X@X ; keep epart = I + X + C/2 in regs;
    //      G = X/6 + C/24 -> nm ; (X^2)^T -> tr ----
    f4v epart[2][2];
    #pragma unroll
    for (int i = 0; i < 2; ++i)
        #pragma unroll
        for (int j = 0; j < 2; ++j) acc[i][j] = z4;
    mm_full(nm_hi, nm_lo, tr_hi, tr_lo, acc, rb, cb, lane);
    __syncthreads();
    float gv[2][2][4];
    #pragma unroll
    for (int mi = 0; mi < 2; ++mi)
        #pragma unroll
        for (int ni = 0; ni < 2; ++ni)
            #pragma unroll
            for (int r = 0; r < 4; ++r) {
                const int row = rb + mi * 16 + quad * 4 + r;
                const int col = cb + ni * 16 + l15;
                const float xq = upbf(nm_hi[row * LDA + col]) + upbf(nm_lo[row * LDA + col]);
                const float c2 = acc[mi][ni][r];
                float ep = xq + 0.5f * c2;
                if (row == col) ep += 1.f;
                epart[mi][ni][r] = ep;
                gv[mi][ni][r] = xq * (1.f / 6.f) + c2 * (1.f / 24.f);
            }
    __syncthreads();
    #pragma unroll
    for (int mi = 0; mi < 2; ++mi)
        #pragma unroll
        for (int ni = 0; ni < 2; ++ni)
            #pragma unroll
            for (int r = 0; r < 4; ++r) {
                const int row = rb + mi * 16 + quad * 4 + r;
                const int col = cb + ni * 16 + l15;
                put2(nm_hi, nm_lo, row * LDA + col, gv[mi][ni][r]);    // G
                put2(tr_hi, tr_lo, col * LDA + row, acc[mi][ni][r]);   // (X^2)^T
            }
    __syncthreads();

    // ---- Op3: M = epart + G@X^2 -> nm + tr ----
    #pragma unroll
    for (int i = 0; i < 2; ++i)
        #pragma unroll
        for (int j = 0; j < 2; ++j) acc[i][j] = z4;
    mm_full(nm_hi, nm_lo, tr_hi, tr_lo, acc, rb, cb, lane);
    __syncthreads();
    #pragma unroll
    for (int mi = 0; mi < 2; ++mi)
        #pragma unroll
        for (int ni = 0; ni < 2; ++ni)
            #pragma unroll
            for (int r = 0; r < 4; ++r) {
                const int row = rb + mi * 16 + quad * 4 + r;
                const int col = cb + ni * 16 + l15;
                const float v = epart[mi][ni][r] + acc[mi][ni][r];
                put2(nm_hi, nm_lo, row * LDA + col, v);
                put2(tr_hi, tr_lo, col * LDA + row, v);
            }
    __syncthreads();

    // ---- u1 = M z (fp32 from trans planes) -> ht slot 0, sidx 0 ----
    if (t < 2 * DIM) {
        const int c = t >> 7, o = t & 127;
        float a = 0.f;
        #pragma unroll 4
        for (int i = 0; i < DIM; ++i)
            a += (upbf(tr_hi[i * LDA + o]) + upbf(tr_lo[i * LDA + o])) * s_z[c * DIM + i];
        put2(ht_hi, ht_lo, (c * 16) * LDA + o, a);
        write_out(outF, b, 0, o, c, a, interleaved, out_size);
    }
    __syncthreads();

    // ---- stages: seed round (J = 2^k, W = M^J) FUSED with squaring ----
    #pragma unroll
    for (int stage = 0; stage < 4; ++stage) {
        const int J = 1 << stage;
        // phase A (reads only): seed mat-vecs + squaring matmul
        const f4v sv = mm_rw(nm_hi, nm_lo, ht_hi, ht_lo, sst, ci, lane);
        #pragma unroll
        for (int i = 0; i < 2; ++i)
            #pragma unroll
            for (int j = 0; j < 2; ++j) acc[i][j] = z4;
        mm_full(nm_hi, nm_lo, tr_hi, tr_lo, acc, rb, cb, lane);
        __syncthreads();
        // phase B (writes): ht slots [J..2J) ; nm/tr <- M^(2J)
        if (l15 < J) {
            #pragma unroll
            for (int r = 0; r < 4; ++r) {
                const int o = sst * 16 + quad * 4 + r;
                put2(ht_hi, ht_lo, (ci * 16 + l15 + J) * LDA + o, sv[r]);
                write_out(outF, b, l15 + J, o, ci, sv[r], interleaved, out_size);
            }
        }
        #pragma unroll
        for (int mi = 0; mi < 2; ++mi)
            #pragma unroll
            for (int ni = 0; ni < 2; ++ni)
                #pragma unroll
                for (int r = 0; r < 4; ++r) {
                    const int row = rb + mi * 16 + quad * 4 + r;
                    const int col = cb + ni * 16 + l15;
                    put2(nm_hi, nm_lo, row * LDA + col, acc[mi][ni][r]);
                    if (stage < 3)   // final squaring's transpose is never read
                        put2(tr_hi, tr_lo, col * LDA + row, acc[mi][ni][r]);
                }
        __syncthreads();
    }

    // ---- 7 windows: all 32 slots <- M^16 @ slots (in place), sidx = 16q+slot ----
    for (int q = 1; q <= 7; ++q) {
        const f4v sv = mm_rw(nm_hi, nm_lo, ht_hi, ht_lo, sst, ci, lane);
        __syncthreads();
        #pragma unroll
        for (int r = 0; r < 4; ++r) {
            const int o = sst * 16 + quad * 4 + r;
            put2(ht_hi, ht_lo, (ci * 16 + l15) * LDA + o, sv[r]);
            write_out(outF, b, 16 * q + l15, o, ci, sv[r], interleaved, out_size);
        }
        __syncthreads();
    }
}

// ================= host =================
extern "C" void kernel_launch(void* const* d_in, const int* in_sizes, int n_in,
                              void* d_out, int out_size, void* d_ws, size_t ws_size,
                              hipStream_t stream)
{
    (void)in_sizes; (void)n_in; (void)d_ws; (void)ws_size;
    const float* z0r = (const float*)d_in[0];
    const float* z0i = (const float*)d_in[1];
    const float* ts  = (const float*)d_in[2];
    const float* kco = (const float*)d_in[3];
    const float* rco = (const float*)d_in[4];
    const float* alp = (const float*)d_in[5];
    const float* bet = (const float*)d_in[6];
    const float* KB  = (const float*)d_in[7];
    const float* RB  = (const float*)d_in[8];
    float* outF = (float*)d_out;

    const int interleaved = (out_size >= 2 * BATCH * SSTEPS * DIM) ? 1 : 0;

    htg_mfma<<<dim3(BATCH), dim3(1024), 0, stream>>>(
        z0r, z0i, ts, kco, rco, alp, bet, KB, RB, outF, interleaved, out_size);
}